// Round 1
// baseline (56.451 us; speedup 1.0000x reference)
//
#include <hip/hip_runtime.h>
#include <hip/hip_bf16.h>

#define NNODES 50000
#define NEDGES 200000
#define KTOT 544            // 512 outer-product + 32 bias-extension
#define WCT_PAD 552         // LDS row stride (bf16 units), breaks bank alignment
#define HROW 40             // h-tile LDS row stride (bf16 units) = 80B, gcd(20,32)=4 -> <=2-way
#define TILE_EDGES 64
#define TILES_PER_BLOCK 5
#define NBLOCKS 625         // 625 * 5 * 64 = 200000 edges, no tail

using f32x4 = __attribute__((ext_vector_type(4))) float;
using s16x8 = __attribute__((ext_vector_type(8))) short;

__device__ __forceinline__ short f2bf(float f) {
    unsigned int u = __builtin_bit_cast(unsigned int, f);
    u = (u + 0x7FFFu + ((u >> 16) & 1u)) >> 16;   // round-to-nearest-even
    return (short)u;
}

// Build WcT[n][c] (bf16), n in [0,32) outputs, c in [0,544) contraction index.
// c < 512: c = i*16 + kk  ->  W_edge[kk, i*32+n];  c >= 512: b_edge[(c-512)*32+n]
__global__ void prep_wct_kernel(const float* __restrict__ W_edge,
                                const float* __restrict__ b_edge,
                                unsigned short* __restrict__ wct) {
    int gid = blockIdx.x * 256 + threadIdx.x;
    if (gid >= 32 * KTOT) return;
    int n = gid / KTOT;
    int c = gid - n * KTOT;
    float v;
    if (c < 512) v = W_edge[(c & 15) * 1024 + (c >> 4) * 32 + n];
    else         v = b_edge[(c - 512) * 32 + n];
    wct[n * KTOT + c] = (unsigned short)f2bf(v);
}

__global__ __launch_bounds__(256) void edge_kernel(
    const float* __restrict__ feat, const float* __restrict__ efeat,
    const int* __restrict__ src, const int* __restrict__ dst,
    const unsigned short* __restrict__ wct_g,
    float* __restrict__ agg, float* __restrict__ deg) {

    __shared__ __align__(16) unsigned short wct_lds[32 * WCT_PAD]; // 35328 B
    __shared__ __align__(16) unsigned short h_lds[TILE_EDGES * HROW]; // 5120 B
    __shared__ int dst_lds[TILE_EDGES];

    const int t = threadIdx.x;

    // Stage WcT global->LDS once per block (rows of 272 dwords -> padded 276)
    {
        const unsigned int* gsrc = (const unsigned int*)wct_g;
        unsigned int* ldst = (unsigned int*)wct_lds;
        int n = t >> 3, sub = t & 7;
        int gb = n * (KTOT / 2) + sub * 34;
        int lb = n * (WCT_PAD / 2) + sub * 34;
        #pragma unroll
        for (int m = 0; m < 34; ++m) ldst[lb + m] = gsrc[gb + m];
    }

    const int lane = t & 63;
    const int wave = t >> 6;
    const int r16  = lane & 15;   // A: edge-row within wave tile; B/D: output col
    const int g    = lane >> 4;   // fragment k-group
    const int wbase = wave * 16;

    for (int q = 0; q < TILES_PER_BLOCK; ++q) {
        const int ebase = (blockIdx.x * TILES_PER_BLOCK + q) * TILE_EDGES;
        __syncthreads();   // prev tile fully consumed (also covers wct staging)

        // Stage h (gathered, bf16) + dst for 64 edges
        {
            int et = t >> 2, p = t & 3;
            int se = src[ebase + et];
            const float* fp = feat + se * 32 + p * 8;
            float4 a = *(const float4*)fp;
            float4 b = *(const float4*)(fp + 4);
            s16x8 hp;
            hp[0] = f2bf(a.x); hp[1] = f2bf(a.y); hp[2] = f2bf(a.z); hp[3] = f2bf(a.w);
            hp[4] = f2bf(b.x); hp[5] = f2bf(b.y); hp[6] = f2bf(b.z); hp[7] = f2bf(b.w);
            *(s16x8*)(void*)(&h_lds[et * HROW + p * 8]) = hp;
            if (t < TILE_EDGES) dst_lds[t] = dst[ebase + t];
        }
        __syncthreads();

        // This lane's A-operand edge
        const int eg = ebase + wbase + r16;
        const float* efp = efeat + eg * 16 + (g & 1) * 8;
        float4 e0 = *(const float4*)efp;
        float4 e1 = *(const float4*)(efp + 4);
        float ef[8] = {e0.x, e0.y, e0.z, e0.w, e1.x, e1.y, e1.z, e1.w};

        const unsigned short* brow0 = wct_lds + r16 * WCT_PAD;
        const unsigned short* brow1 = wct_lds + (16 + r16) * WCT_PAD;
        const unsigned short* hrow  = h_lds + (wbase + r16) * HROW;

        f32x4 acc0 = {0.f, 0.f, 0.f, 0.f};
        f32x4 acc1 = {0.f, 0.f, 0.f, 0.f};

        // X[e, c] = h[i]*ef[kk], c = i*16+kk; lane covers c = 32s + 8g + j
        // => i = 2s + (g>>1), kk = (g&1)*8 + j  (same (g,j)->k map used for B)
        #pragma unroll
        for (int s = 0; s < 16; ++s) {
            const int koff = s * 32 + g * 8;
            s16x8 b0 = *(const s16x8*)(void*)(brow0 + koff);
            s16x8 b1 = *(const s16x8*)(void*)(brow1 + koff);
            unsigned int hu = (unsigned int)hrow[2 * s + (g >> 1)] << 16;
            float hv = __builtin_bit_cast(float, hu);
            s16x8 af;
            #pragma unroll
            for (int j = 0; j < 8; ++j) af[j] = f2bf(hv * ef[j]);
            acc0 = __builtin_amdgcn_mfma_f32_16x16x32_bf16(af, b0, acc0, 0, 0, 0);
            acc1 = __builtin_amdgcn_mfma_f32_16x16x32_bf16(af, b1, acc1, 0, 0, 0);
        }
        { // k-step 16: bias extension, X[e, 512+i] = h[i] (already bf16 in LDS)
            const int koff = 512 + g * 8;
            s16x8 b0 = *(const s16x8*)(void*)(brow0 + koff);
            s16x8 b1 = *(const s16x8*)(void*)(brow1 + koff);
            s16x8 af = *(const s16x8*)(void*)(hrow + g * 8);
            acc0 = __builtin_amdgcn_mfma_f32_16x16x32_bf16(af, b0, acc0, 0, 0, 0);
            acc1 = __builtin_amdgcn_mfma_f32_16x16x32_bf16(af, b1, acc1, 0, 0, 0);
        }

        // Epilogue: D row = (lane>>4)*4 + r, col = lane&15 (m89-verified layout)
        #pragma unroll
        for (int r = 0; r < 4; ++r) {
            int dn = dst_lds[wbase + g * 4 + r];
            atomicAdd(&agg[dn * 32 + r16], acc0[r]);
            atomicAdd(&agg[dn * 32 + 16 + r16], acc1[r]);
        }
        if (lane < 16) atomicAdd(&deg[dst_lds[wbase + lane]], 1.0f);
    }
}

__global__ void finalize_kernel(float* __restrict__ out,
                                const float* __restrict__ deg,
                                const float* __restrict__ bias) {
    int idx = blockIdx.x * 256 + threadIdx.x;
    if (idx >= NNODES * 32) return;
    out[idx] = out[idx] / fmaxf(deg[idx >> 5], 1.0f) + bias[idx & 31];
}

extern "C" void kernel_launch(void* const* d_in, const int* in_sizes, int n_in,
                              void* d_out, int out_size, void* d_ws, size_t ws_size,
                              hipStream_t stream) {
    const float* feat   = (const float*)d_in[0];
    const float* efeat  = (const float*)d_in[1];
    const int*   src    = (const int*)d_in[2];
    const int*   dst    = (const int*)d_in[3];
    const float* W_edge = (const float*)d_in[4];
    const float* b_edge = (const float*)d_in[5];
    const float* bias   = (const float*)d_in[6];

    float* out = (float*)d_out;
    float* deg = (float*)d_ws;                                   // 200 KB
    unsigned short* wct = (unsigned short*)((char*)d_ws + 262144); // 34816 B

    // Zero accumulators (harness poisons once; we must init every launch)
    hipMemsetAsync(out, 0, (size_t)NNODES * 32 * sizeof(float), stream);
    hipMemsetAsync(deg, 0, (size_t)NNODES * sizeof(float), stream);

    prep_wct_kernel<<<(32 * KTOT + 255) / 256, 256, 0, stream>>>(W_edge, b_edge, wct);
    edge_kernel<<<NBLOCKS, 256, 0, stream>>>(feat, efeat, src, dst, wct, out, deg);
    finalize_kernel<<<(NNODES * 32 + 255) / 256, 256, 0, stream>>>(out, deg, bias);
}

// Round 3
// 55.103 us; speedup vs baseline: 1.0245x; 1.0245x over previous
//
#include <hip/hip_runtime.h>
#include <hip/hip_bf16.h>

#define NNODES 50000
#define NEDGES 200000
#define WCT_ROW 552                      // f16 units; 1104B row, phase gcd(20,32)=4 -> conflict-free reads
#define WCT_BYTES (32 * WCT_ROW * 2)     // 35328
#define HROW 40                          // f16 units; 80B row (16B-aligned, conflict-free phases)
#define TILE_EDGES 64
#define NBLOCKS (NEDGES / TILE_EDGES)    // 3125

#define DEG_OFF (NNODES * 32 * 4)            // agg: 6.4 MB at ws+0
#define ZERO_BYTES (DEG_OFF + NNODES * 4)    // agg + deg = 6.6 MB zeroed
#define WCT_OFF 6600192                      // 16B-aligned, past zeroed region

using f32x4 = __attribute__((ext_vector_type(4))) float;
using f16x2 = __attribute__((ext_vector_type(2))) _Float16;
using f16x4 = __attribute__((ext_vector_type(4))) _Float16;
using f16x8 = __attribute__((ext_vector_type(8))) _Float16;

__device__ __forceinline__ f16x2 pkrtz(float a, float b) {
    return __builtin_bit_cast(f16x2, __builtin_amdgcn_cvt_pkrtz(a, b));
}

// Build padded WcT[n][c] in f16. c<512: c=i*16+kk -> W_edge[kk,i*32+n];
// 512<=c<544: b_edge[(c-512)*32+n]; 544..551: zero pad.
__global__ void prep_wct_kernel(const float* __restrict__ W_edge,
                                const float* __restrict__ b_edge,
                                _Float16* __restrict__ wct) {
    int gid = blockIdx.x * 256 + threadIdx.x;
    if (gid >= 32 * WCT_ROW) return;
    int n = gid / WCT_ROW;
    int c = gid - n * WCT_ROW;
    float v = 0.0f;
    if (c < 512)      v = W_edge[(c & 15) * 1024 + (c >> 4) * 32 + n];
    else if (c < 544) v = b_edge[(c - 512) * 32 + n];
    wct[gid] = (_Float16)v;
}

__device__ __forceinline__ void gload_lds16(const void* g, void* l) {
    __builtin_amdgcn_global_load_lds(
        (const __attribute__((address_space(1))) unsigned int*)g,
        (__attribute__((address_space(3))) unsigned int*)l, 16, 0, 0);
}

__global__ __launch_bounds__(256, 4) void edge_kernel(
    const float* __restrict__ feat, const float* __restrict__ efeat,
    const int* __restrict__ src, const int* __restrict__ dst,
    const _Float16* __restrict__ wct_g,
    float* __restrict__ agg, float* __restrict__ deg) {

    __shared__ __align__(16) unsigned short wct_lds[32 * WCT_ROW]; // 35328 B
    __shared__ __align__(16) unsigned short h_lds[TILE_EDGES * HROW]; // 5120 B
    __shared__ int dst_lds[TILE_EDGES];

    const int t = threadIdx.x;
    const int lane = t & 63;
    const int wave = t >> 6;
    const int ebase = blockIdx.x * TILE_EDGES;

    // Stage WcT global->LDS async, 1KB chunks per wave, 16B/lane (linear dest)
    {
        const char* gsrc = (const char*)wct_g;
        char* lbase = (char*)wct_lds;
        #pragma unroll
        for (int c = 0; c < 9; ++c) {
            int chunk = wave + c * 4;            // wave-uniform
            if (chunk < 35) {
                int boff = (chunk << 10) + lane * 16;
                if (boff < WCT_BYTES) gload_lds16(gsrc + boff, lbase + boff);
            }
        }
    }

    // Stage gathered h (f32 -> f16 packed) + dst for 64 edges
    {
        int et = t >> 2, p = t & 3;
        int se = src[ebase + et];
        const float* fp = feat + se * 32 + p * 8;
        float4 a = *(const float4*)fp;
        float4 b = *(const float4*)(fp + 4);
        uint4 hp;
        hp.x = __builtin_bit_cast(unsigned int, pkrtz(a.x, a.y));
        hp.y = __builtin_bit_cast(unsigned int, pkrtz(a.z, a.w));
        hp.z = __builtin_bit_cast(unsigned int, pkrtz(b.x, b.y));
        hp.w = __builtin_bit_cast(unsigned int, pkrtz(b.z, b.w));
        *(uint4*)(void*)(h_lds + et * HROW + p * 8) = hp;
        if (t < TILE_EDGES) dst_lds[t] = dst[ebase + t];
    }

    const int r16 = lane & 15;   // A: edge row in wave tile; B/D: output col
    const int g   = lane >> 4;   // fragment k-group
    const int wbase = wave * 16;
    const int eg = ebase + wbase + r16;

    // ef fragment (independent of LDS; overlaps staging latency)
    const float* efp = efeat + eg * 16 + (g & 1) * 8;
    float4 e0 = *(const float4*)efp;
    float4 e1 = *(const float4*)(efp + 4);
    f16x2 ef2[4] = { pkrtz(e0.x, e0.y), pkrtz(e0.z, e0.w),
                     pkrtz(e1.x, e1.y), pkrtz(e1.z, e1.w) };

    __syncthreads();   // drains global_load_lds (vmcnt) + ds_writes

    // h row -> regs; per-s broadcast half2 of h[2s + (g>>1)]
    unsigned int hbc[16];
    {
        const uint4* hrow = (const uint4*)(void*)(h_lds + (wbase + r16) * HROW);
        unsigned int hw[16];
        #pragma unroll
        for (int q = 0; q < 4; ++q) {
            uint4 v = hrow[q];
            hw[q*4+0] = v.x; hw[q*4+1] = v.y; hw[q*4+2] = v.z; hw[q*4+3] = v.w;
        }
        const bool hi = (g >> 1) & 1;
        #pragma unroll
        for (int s = 0; s < 16; ++s) {
            unsigned int x = hi ? (hw[s] >> 16) : (hw[s] & 0xffffu);
            hbc[s] = x | (x << 16);
        }
    }

    const _Float16* brow0 = (const _Float16*)wct_lds + r16 * WCT_ROW;
    const _Float16* brow1 = (const _Float16*)wct_lds + (16 + r16) * WCT_ROW;

    f32x4 acc0 = {0.f, 0.f, 0.f, 0.f};
    f32x4 acc1 = {0.f, 0.f, 0.f, 0.f};

    // X[e,c] = h[i]*ef[kk], c = 32s + 8g + j  =>  i = 2s+(g>>1), kk = (g&1)*8+j
    // Same (g,j)->c map for A and B => contraction correct for any HW k-layout.
    #pragma unroll
    for (int s = 0; s < 16; ++s) {
        const int koff = s * 32 + g * 8;
        f16x8 b0 = *(const f16x8*)(brow0 + koff);
        f16x8 b1 = *(const f16x8*)(brow1 + koff);
        f16x2 hb = __builtin_bit_cast(f16x2, hbc[s]);
        f16x2 p0 = hb * ef2[0], p1 = hb * ef2[1], p2 = hb * ef2[2], p3 = hb * ef2[3];
        f16x4 lo  = __builtin_shufflevector(p0, p1, 0, 1, 2, 3);
        f16x4 hi4 = __builtin_shufflevector(p2, p3, 0, 1, 2, 3);
        f16x8 af  = __builtin_shufflevector(lo, hi4, 0, 1, 2, 3, 4, 5, 6, 7);
        acc0 = __builtin_amdgcn_mfma_f32_16x16x32_f16(af, b0, acc0, 0, 0, 0);
        acc1 = __builtin_amdgcn_mfma_f32_16x16x32_f16(af, b1, acc1, 0, 0, 0);
    }
    {   // bias-extension k-step: X[e, 512+i] = h[i]
        const int koff = 512 + g * 8;
        f16x8 b0 = *(const f16x8*)(brow0 + koff);
        f16x8 b1 = *(const f16x8*)(brow1 + koff);
        f16x8 af = *(const f16x8*)(void*)((const _Float16*)h_lds + (wbase + r16) * HROW + g * 8);
        acc0 = __builtin_amdgcn_mfma_f32_16x16x32_f16(af, b0, acc0, 0, 0, 0);
        acc1 = __builtin_amdgcn_mfma_f32_16x16x32_f16(af, b1, acc1, 0, 0, 0);
    }

    // D layout (m89): col = lane&15, row = (lane>>4)*4 + r
    #pragma unroll
    for (int r = 0; r < 4; ++r) {
        int dn = dst_lds[wbase + g * 4 + r];
        atomicAdd(&agg[dn * 32 + r16], acc0[r]);
        atomicAdd(&agg[dn * 32 + 16 + r16], acc1[r]);
    }
    if (lane < 16) atomicAdd(&deg[dst_lds[wbase + lane]], 1.0f);
}

__global__ void finalize_kernel(const float* __restrict__ agg,
                                const float* __restrict__ deg,
                                const float* __restrict__ bias,
                                float* __restrict__ out) {
    int gid = blockIdx.x * 256 + threadIdx.x;
    if (gid >= NNODES * 8) return;
    int node = gid >> 3;
    int c = (gid & 7) * 4;
    float inv = 1.0f / fmaxf(deg[node], 1.0f);
    float4 a = *(const float4*)(agg + node * 32 + c);
    float4 b = *(const float4*)(bias + c);
    float4 o = { a.x * inv + b.x, a.y * inv + b.y, a.z * inv + b.z, a.w * inv + b.w };
    *(float4*)(out + node * 32 + c) = o;
}

extern "C" void kernel_launch(void* const* d_in, const int* in_sizes, int n_in,
                              void* d_out, int out_size, void* d_ws, size_t ws_size,
                              hipStream_t stream) {
    const float* feat   = (const float*)d_in[0];
    const float* efeat  = (const float*)d_in[1];
    const int*   src    = (const int*)d_in[2];
    const int*   dst    = (const int*)d_in[3];
    const float* W_edge = (const float*)d_in[4];
    const float* b_edge = (const float*)d_in[5];
    const float* bias   = (const float*)d_in[6];

    float*     agg = (float*)d_ws;
    float*     deg = (float*)((char*)d_ws + DEG_OFF);
    _Float16*  wct = (_Float16*)((char*)d_ws + WCT_OFF);
    float*     out = (float*)d_out;

    (void)hipMemsetAsync(d_ws, 0, ZERO_BYTES, stream);
    prep_wct_kernel<<<(32 * WCT_ROW + 255) / 256, 256, 0, stream>>>(W_edge, b_edge, wct);
    edge_kernel<<<NBLOCKS, 256, 0, stream>>>(feat, efeat, src, dst, wct, agg, deg);
    finalize_kernel<<<(NNODES * 8 + 255) / 256, 256, 0, stream>>>(agg, deg, bias, out);
}